// Round 9
// baseline (211.277 us; speedup 1.0000x reference)
//
#include <hip/hip_runtime.h>

#define NB   4
#define SEQ  4096
#define EMB  1024
#define HS   64

typedef __attribute__((ext_vector_type(8))) short bf16x8;   // 8 bf16 = 4 VGPRs
typedef __attribute__((ext_vector_type(4))) float f32x4;    // MFMA C/D

__device__ inline unsigned short f2bf(float f) {  // fp32 -> bf16 RNE
  unsigned int u = __float_as_uint(f);
  u += 0x7fffu + ((u >> 16) & 1u);
  return (unsigned short)(u >> 16);
}
__device__ inline float bf2f(unsigned short h) {
  return __uint_as_float(((unsigned int)h) << 16);
}
// 16B-chunk index in a [row][64] bf16 LDS tile, XOR-swizzled over row&7.
__device__ inline int swzi64(int row, int c) {
  return row * 64 + ((c ^ (row & 7)) << 3);
}
// same for [row][32] tiles (4 chunks/row, swizzle over (row>>1)&3)
__device__ inline int swzi32(int row, int c) {
  return row * 32 + ((c ^ ((row >> 1) & 3)) << 3);
}
// [row][128] tiles (16 chunks/row, swizzle over row&7)
__device__ inline int swzi128(int row, int c) {
  return row * 128 + ((c ^ (row & 7)) << 3);
}
// Async global->LDS 16B. LDS dest wave-uniform; lane i lands at +16*i.
__device__ inline void gld16(const unsigned short* g, unsigned short* l) {
  __builtin_amdgcn_global_load_lds(
      (const __attribute__((address_space(1))) void*)g,
      (__attribute__((address_space(3))) void*)l, 16, 0, 0);
}

// ---------------------------------------------------------------------------
// W prep: split Wq*scale*log2e | Wk | Wv into bf16 hi/lo [192][1024].
// ---------------------------------------------------------------------------
__global__ __launch_bounds__(256) void wprep(
    const float* __restrict__ Wk, const float* __restrict__ Wq,
    const float* __restrict__ Wv,
    unsigned short* __restrict__ Wh, unsigned short* __restrict__ Wl) {
  int i = blockIdx.x * 256 + threadIdx.x;  // float4 id, 192*1024/4 = 49152
  int e = i >> 8, c = i & 255;
  float4 v;
  float sc = 1.0f;
  if (e < 64)       { v = ((const float4*)Wq)[e * 256 + c];
                      sc = 0.18033688011112042f; }  // (1/sqrt(64))*log2(e)
  else if (e < 128)   v = ((const float4*)Wk)[(e - 64) * 256 + c];
  else                v = ((const float4*)Wv)[(e - 128) * 256 + c];
  v.x *= sc; v.y *= sc; v.z *= sc; v.w *= sc;
  ushort4 hv, lv;
  hv.x = f2bf(v.x); lv.x = f2bf(v.x - bf2f(hv.x));
  hv.y = f2bf(v.y); lv.y = f2bf(v.y - bf2f(hv.y));
  hv.z = f2bf(v.z); lv.z = f2bf(v.z - bf2f(hv.z));
  hv.w = f2bf(v.w); lv.w = f2bf(v.w - bf2f(hv.w));
  *(ushort4*)&Wh[i * 4] = hv;
  *(ushort4*)&Wl[i * 4] = lv;
}

// ---------------------------------------------------------------------------
// Single-pass fused QKV GEMM, round 9: 4 waves/SIMD occupancy version.
// m-tile 16 (grid 1024 = 4 blocks/CU), Wl in REGISTERS (contiguous ushort8
// per wave, proven r3), Wh via gld16 LDS (self-staged per wave -> counted
// vmcnt works), X in LDS (shared fp32->hi/lo). LDS 28KB -> LDS cap 5
// blocks/CU, grid gives 4 resident = 16 waves/CU = 4 waves/SIMD (2x r2).
// Pipeline = r2 scheme: issueW(s+1)+loadBl(s+1)+writeX(px) (px-use emits
// counted vmcnt, leaves next-stage loads in flight), raw lgkmcnt(0)+
// s_barrier (NO vmcnt drain). 9 MFMA/step/wave (acc 1x3).
// ---------------------------------------------------------------------------
#define XhSp(p) ((unsigned short*)(SM + (p) * 1024))
#define XlSp(p) ((unsigned short*)(SM + 2048 + (p) * 1024))
#define WhSp(p) ((unsigned short*)(SM + 4096 + (p) * 12288))

__global__ __launch_bounds__(256, 4) void qkv_x1(
    const float* __restrict__ x,
    const unsigned short* __restrict__ Wh, const unsigned short* __restrict__ Wl,
    unsigned short* __restrict__ qh, unsigned short* __restrict__ ql,
    unsigned short* __restrict__ kh, unsigned short* __restrict__ kl,
    unsigned short* __restrict__ vt) {
  __shared__ __align__(16) unsigned char SM[28672];

  const int t  = threadIdx.x;
  const int l  = t & 63;
  const int li = l & 15;
  const int g  = l >> 4;
  const int w  = t >> 6;         // 0..3
  const int m0 = blockIdx.x * 16;
  const int b  = m0 >> 12;
  const int n0 = m0 & 4095;

  // x load/convert map: thread -> one float2 of the 16x32 tile
  const int xrow = t >> 4;       // 0..15
  const int c2   = t & 15;       // float-pair index 0..15
  const float* xp = x + (m0 + xrow) * EMB + 2 * c2;
  const int xaddr = xrow * 32 + (((c2 >> 2) ^ ((xrow >> 1) & 3)) << 3)
                    + (c2 & 3) * 2;

  // Wh gld16 lane-constant (seg = 16 W-rows x 32 k = 1KB)
  const int wconst = (l >> 2) * EMB + (((l & 3) ^ ((l >> 3) & 3)) << 3);

  // Wl direct-to-reg row bases (this wave's 3 B-columns, this lane's row)
  const unsigned short* const WlR0 = Wl + (48 * w + li) * EMB + 8 * g;
  const unsigned short* const WlR1 = Wl + (48 * w + 16 + li) * EMB + 8 * g;
  const unsigned short* const WlR2 = Wl + (48 * w + 32 + li) * EMB + 8 * g;

  f32x4 acc[3];
#pragma unroll
  for (int j = 0; j < 3; ++j) acc[j] = (f32x4){0.f, 0.f, 0.f, 0.f};

  const int rB0 = 48 * w + li, rB1 = rB0 + 16, rB2 = rB0 + 32;

  auto issueW = [&](int s, int p) {
    const int ko = s * 32;
#pragma unroll
    for (int i = 0; i < 3; ++i) {
      const int seg = 3 * w + i;
      gld16(Wh + 16 * seg * EMB + wconst + ko, WhSp(p) + seg * 512);
    }
  };
  auto loadBl = [&](int s, bf16x8 (&B)[3]) {
    const int ko = s * 32;
    B[0] = *(const bf16x8*)&WlR0[ko];
    B[1] = *(const bf16x8*)&WlR1[ko];
    B[2] = *(const bf16x8*)&WlR2[ko];
  };
  auto writeX = [&](float2 v, int p) {
    unsigned short h0 = f2bf(v.x), h1 = f2bf(v.y);
    unsigned short e0 = f2bf(v.x - bf2f(h0)), e1 = f2bf(v.y - bf2f(h1));
    *(unsigned*)&XhSp(p)[xaddr] = (unsigned)h0 | ((unsigned)h1 << 16);
    *(unsigned*)&XlSp(p)[xaddr] = (unsigned)e0 | ((unsigned)e1 << 16);
  };

  bf16x8 BlA[3], BlB[3];
  issueW(0, 0);
  loadBl(0, BlA);
  writeX(*(const float2*)xp, 0);
  float2 px = *(const float2*)(xp + 32);   // x(1)
  __syncthreads();                         // prologue-only full drain

  auto step = [&](int s, bf16x8 (&Blc)[3], bf16x8 (&Bln)[3]) {
    const int p = s & 1;
    if (s < 31) {
      issueW(s + 1, p ^ 1);     // 3 gld16 -- fly across the barrier
      loadBl(s + 1, Bln);       // 3 reg loads -- fly across the barrier
      writeX(px, p ^ 1);        // px-use emits counted vmcnt: W(s)+Bl(s) landed
      if (s < 30) px = *(const float2*)(xp + (s + 2) * 32);
    } else {
      asm volatile("s_waitcnt vmcnt(0)" ::: "memory");  // tail: W(31) landed
    }
    __builtin_amdgcn_sched_barrier(0);  // ds_reads stay below the waits

    bf16x8 ah = *(const bf16x8*)&XhSp(p)[swzi32(li, g)];
    bf16x8 al = *(const bf16x8*)&XlSp(p)[swzi32(li, g)];
    bf16x8 bh0 = *(const bf16x8*)&WhSp(p)[swzi32(rB0, g)];
    bf16x8 bh1 = *(const bf16x8*)&WhSp(p)[swzi32(rB1, g)];
    bf16x8 bh2 = *(const bf16x8*)&WhSp(p)[swzi32(rB2, g)];

    __builtin_amdgcn_s_setprio(1);
    acc[0] = __builtin_amdgcn_mfma_f32_16x16x32_bf16(ah, bh0,    acc[0], 0,0,0);
    acc[0] = __builtin_amdgcn_mfma_f32_16x16x32_bf16(ah, Blc[0], acc[0], 0,0,0);
    acc[0] = __builtin_amdgcn_mfma_f32_16x16x32_bf16(al, bh0,    acc[0], 0,0,0);
    acc[1] = __builtin_amdgcn_mfma_f32_16x16x32_bf16(ah, bh1,    acc[1], 0,0,0);
    acc[1] = __builtin_amdgcn_mfma_f32_16x16x32_bf16(ah, Blc[1], acc[1], 0,0,0);
    acc[1] = __builtin_amdgcn_mfma_f32_16x16x32_bf16(al, bh1,    acc[1], 0,0,0);
    acc[2] = __builtin_amdgcn_mfma_f32_16x16x32_bf16(ah, bh2,    acc[2], 0,0,0);
    acc[2] = __builtin_amdgcn_mfma_f32_16x16x32_bf16(ah, Blc[2], acc[2], 0,0,0);
    acc[2] = __builtin_amdgcn_mfma_f32_16x16x32_bf16(al, bh2,    acc[2], 0,0,0);
    __builtin_amdgcn_s_setprio(0);

    // Raw barrier: X(s+1) ds_writes visible (lgkmcnt) WITHOUT draining the
    // in-flight W(s+1)/Bl(s+1)/px vmem ops.
    asm volatile("s_waitcnt lgkmcnt(0)" ::: "memory");
    __builtin_amdgcn_s_barrier();
    __builtin_amdgcn_sched_barrier(0);
  };

  for (int s2 = 0; s2 < 16; ++s2) {
    step(2 * s2,     BlA, BlB);
    step(2 * s2 + 1, BlB, BlA);
  }

  // Epilogue: D[m=4g+r][n=48w+16j+li]
#pragma unroll
  for (int j = 0; j < 3; ++j) {
    const int H3 = 48 * w + 16 * j + li;
#pragma unroll
    for (int r = 0; r < 4; ++r) {
      const int mrow = 4 * g + r;
      const float vv = acc[j][r];
      if (H3 < 64) {
        const unsigned short hb = f2bf(vv);
        const int off = (b * SEQ + n0 + mrow) * HS + H3;
        qh[off] = hb; ql[off] = f2bf(vv - bf2f(hb));
      } else if (H3 < 128) {
        const unsigned short hb = f2bf(vv);
        const int off = (b * SEQ + n0 + mrow) * HS + (H3 - 64);
        kh[off] = hb; kl[off] = f2bf(vv - bf2f(hb));
      } else {
        vt[(b * HS + (H3 - 128)) * SEQ + n0 + mrow] = f2bf(vv);
      }
    }
  }
}

// ---------------------------------------------------------------------------
// Flash attention, round-8 structure (best): 16 waves (1024 thr) = 4
// waves/SIMD. QK wave (qg=w&1, kf=w>>1): 32q x 16 keys; PV wave (qg, ks2,
// hh): 32q x 32keys x 32h. Deferred PV (T15), V 3-buf, Pt 2 time-parities,
// one barrier/iter. UNCHANGED this round.
// ---------------------------------------------------------------------------
__global__ __launch_bounds__(1024) void attn_mfma(
    const unsigned short* __restrict__ qh, const unsigned short* __restrict__ ql,
    const unsigned short* __restrict__ kh, const unsigned short* __restrict__ kl,
    const unsigned short* __restrict__ vt, float* __restrict__ out) {
  __shared__ __align__(16) unsigned char SM[155648];
  // layout: Kh[p] @ p*16384 (2x16KB)           [0 .. 32K)
  //         Kl[p] @ 32768 + p*16384 (2x16KB)   [32K .. 64K)
  //         Vt[v] @ 65536 + v*16384 (3x16KB)   [64K .. 112K)
  //         Pt    @ 114688, 8 slabs x 2 time-parities x 1280 ush (40KB)
  unsigned short* const PtS = (unsigned short*)(SM + 114688);

  const int t  = threadIdx.x;
  const int l  = t & 63;
  const int li = l & 15;
  const int g  = l >> 4;
  const int w  = t >> 6;        // 0..15
  const int qg = w & 1;         // QK role: q-half
  const int kf = w >> 1;        // QK role: 16-key group 0..7
  const int ks2 = (w >> 1) & 3; // PV role: 32-key slice
  const int hh  = w >> 3;       // PV role: 32-h half
  const int b  = blockIdx.y;
  const int q0 = blockIdx.x << 6;

  // Persistent Q fragments, 2 q-sets (B[k=h][n=q], n=li), rows 32qg+16qs+li.
  bf16x8 qfh[2][2], qfl[2][2];
#pragma unroll
  for (int qs = 0; qs < 2; ++qs) {
    const unsigned short* qrh = qh + (b * SEQ + q0 + 32 * qg + 16 * qs + li) * HS;
    const unsigned short* qrl = ql + (b * SEQ + q0 + 32 * qg + 16 * qs + li) * HS;
    qfh[qs][0] = *(const bf16x8*)&qrh[8 * g];
    qfh[qs][1] = *(const bf16x8*)&qrh[32 + 8 * g];
    qfl[qs][0] = *(const bf16x8*)&qrl[8 * g];
    qfl[qs][1] = *(const bf16x8*)&qrl[32 + 8 * g];
  }

  // gld16 lane constants. K segs: 8 key-rows x 64 h = 1KB; seg = w.
  const int kconst = (l >> 3) * HS + (((l & 7) ^ (l >> 3)) << 3);
  // V segs: 4 h-rows x 128 keys = 1KB; chunk perm depends on seg parity.
  const int rowl = l >> 4, slot = l & 15;
  const int vc = (w & 1) ? rowl * SEQ + ((slot ^ (4 + rowl)) << 3)
                         : rowl * SEQ + ((slot ^ rowl) << 3);
  const unsigned short* khB = kh + b * SEQ * HS;
  const unsigned short* klB = kl + b * SEQ * HS;
  const unsigned short* vtB = vt + b * HS * SEQ;

  f32x4 O[2][2];                // [ht2][qs-of-pg]
#pragma unroll
  for (int i = 0; i < 2; ++i) {
    O[i][0] = (f32x4){0.f, 0.f, 0.f, 0.f};
    O[i][1] = (f32x4){0.f, 0.f, 0.f, 0.f};
  }
  float lp0 = 0.f, lp1 = 0.f;

  // Pt write constants: slab = qg + 2*(kf>>1); chunk c = 2*(kf&1) + (g>>1).
  const int slabW = qg + 2 * (kf >> 1);
  const int cW = 2 * (kf & 1) + (g >> 1);
  const int subW = (g & 1) << 2;

  auto stage = [&](int it, int pK, int vb) {
    const int kt0 = it << 7;  // 128 keys per tile
    unsigned short* const KhP = (unsigned short*)(SM + pK * 16384);
    unsigned short* const KlP = (unsigned short*)(SM + 32768 + pK * 16384);
    unsigned short* const VtP = (unsigned short*)(SM + 65536 + vb * 16384);
    gld16(khB + (kt0 + 8 * w) * HS + kconst, KhP + w * 512);
    gld16(klB + (kt0 + 8 * w) * HS + kconst, KlP + w * 512);
    gld16(vtB + 4 * w * SEQ + kt0 + vc, VtP + w * 512);
  };

  // PV of a prior tile: Pt time-parity `par`, V buffer `vb`.
  auto PV = [&](int par, int vb) {
    unsigned short* const PtP = PtS + (qg + 2 * ks2) * 2560 + par * 1280;
    unsigned short* const VtP = (unsigned short*)(SM + 65536 + vb * 16384);
    bf16x8 pb0 = *(const bf16x8*)&PtP[li * 40 + ((g ^ (li & 3)) << 3)];
    const int r1 = 16 + li;
    bf16x8 pb1 = *(const bf16x8*)&PtP[r1 * 40 + ((g ^ (r1 & 3)) << 3)];
    __builtin_amdgcn_s_setprio(1);
#pragma unroll
    for (int ht2 = 0; ht2 < 2; ++ht2) {
      const int vrow = 32 * hh + 16 * ht2 + li;
      bf16x8 va = *(const bf16x8*)&VtP[swzi128(vrow, 4 * ks2 + g)];
      O[ht2][0] = __builtin_amdgcn_mfma_f32_16x16x32_bf16(va, pb0, O[ht2][0], 0,0,0);
      O[ht2][1] = __builtin_amdgcn_mfma_f32_16x16x32_bf16(va, pb1, O[ht2][1], 0,0,0);
    }
    __builtin_amdgcn_s_setprio(0);
  };

  stage(0, 0, 0);
  __syncthreads();            // drains tile 0 -> K[0], V[0] ready

  int vbn = 1;                // (it+1)%3
  int vbp = 2;                // (it-1)%3 (unused at it=0)
  for (int it = 0; it < 32; ++it) {
    const int p = it & 1;
    if (it < 31) stage(it + 1, p ^ 1, vbn);  // flies during compute of tile it

    unsigned short* const KhS = (unsigned short*)(SM + p * 16384);
    unsigned short* const KlS = (unsigned short*)(SM + 32768 + p * 16384);

    // QK^T(it): this wave's 16 keys (16kf + 4g + r) x its 32 q.
    f32x4 S[2];
    S[0] = (f32x4){-32.f, -32.f, -32.f, -32.f};
    S[1] = (f32x4){-32.f, -32.f, -32.f, -32.f};
    __builtin_amdgcn_s_setprio(1);
#pragma unroll
    for (int khf = 0; khf < 2; ++khf) {
      const int row = 16 * kf + li;
      bf16x8 akh = *(const bf16x8*)&KhS[swzi64(row, 4 * khf + g)];
      bf16x8 akl = *(const bf16x8*)&KlS[swzi64(row, 4 * khf + g)];
      S[0] = __builtin_amdgcn_mfma_f32_16x16x32_bf16(akh, qfh[0][khf], S[0], 0,0,0);
      S[0] = __builtin_amdgcn_mfma_f32_16x16x32_bf16(akh, qfl[0][khf], S[0], 0,0,0);
      S[0] = __builtin_amdgcn_mfma_f32_16x16x32_bf16(akl, qfh[0][khf], S[0], 0,0,0);
      S[1] = __builtin_amdgcn_mfma_f32_16x16x32_bf16(akh, qfh[1][khf], S[1], 0,0,0);
      S[1] = __builtin_amdgcn_mfma_f32_16x16x32_bf16(akh, qfl[1][khf], S[1], 0,0,0);
      S[1] = __builtin_amdgcn_mfma_f32_16x16x32_bf16(akl, qfh[1][khf], S[1], 0,0,0);
    }
    __builtin_amdgcn_s_setprio(0);

    // PV of PREVIOUS tile (other time-parity Pt + V[vbp]); independent of
    // S(it) -> overlaps the exp chain below.
    if (it > 0) PV(p ^ 1, vbp);

    // exp2, truncate to bf16, write Pt (parity p), accumulate l.
#pragma unroll
    for (int qs = 0; qs < 2; ++qs) {
      unsigned pu[4];
      float ls = 0.f;
#pragma unroll
      for (int r = 0; r < 4; ++r) {
        const float pe = exp2f(S[qs][r]);
        pu[r] = __float_as_uint(pe);
        ls += __uint_as_float(pu[r] & 0xffff0000u);
      }
      if (qs == 0) lp0 += ls; else lp1 += ls;
      const unsigned p01 = __builtin_amdgcn_perm(pu[1], pu[0], 0x07060302u);
      const unsigned p23 = __builtin_amdgcn_perm(pu[3], pu[2], 0x07060302u);
      const int qrow = 16 * qs + li;
      const int addr = qrow * 40 + (((cW ^ (qrow & 3))) << 3) + subW;
      int2 pv; pv.x = (int)p01; pv.y = (int)p23;
      *(int2*)&PtS[slabW * 2560 + p * 1280 + addr] = pv;
    }

    // ONE barrier/iter: drains tile it+1 staging + orders Pt/V/K reuse.
    __syncthreads();

    vbn = (vbn == 2) ? 0 : vbn + 1;
    vbp = (vbp == 2) ? 0 : vbp + 1;
  }

  // Drain: PV of tile 31 (Pt parity 1, V[31%3=1]).
  PV(1, 1);

  // reduce l over g (wave's 16 keys spread over g-quads)
  lp0 += __shfl_xor(lp0, 16); lp0 += __shfl_xor(lp0, 32);
  lp1 += __shfl_xor(lp1, 16); lp1 += __shfl_xor(lp1, 32);

  // Merge. OTm [0,64K) = K buffers (consumed); Lm 2KB in V[0] (not read by
  // PV(31), which reads V[1]+Pt) -- disjoint, no extra barrier needed.
  float* const OTm = (float*)SM;               // 16 x [32q][32h] f32 = 64KB
  float* const Lm  = (float*)(SM + 65536);     // [16 qk-waves][32 q]
#pragma unroll
  for (int ht2 = 0; ht2 < 2; ++ht2)
#pragma unroll
    for (int qs = 0; qs < 2; ++qs) {
      float4 o4;
      o4.x = O[ht2][qs][0]; o4.y = O[ht2][qs][1];
      o4.z = O[ht2][qs][2]; o4.w = O[ht2][qs][3];
      // sub-array id: (pg*2 + hh)*4 + ks2 ; within: [16qs+li][32h]
      *(float4*)&OTm[(((qg * 2 + hh) * 4 + ks2) << 10)
                     + (16 * qs + li) * 32 + 16 * ht2 + 4 * g] = o4;
    }
  if (g == 0) { Lm[w * 32 + li] = lp0; Lm[w * 32 + 16 + li] = lp1; }
  __syncthreads();

  // final: thread t -> q = t>>4 (64), hseg = (t&15)*4; sum 4 key-slices.
  {
    const int q = t >> 4, hseg = (t & 15) << 2;
    const int qq = q & 31, qgf = q >> 5;
    const int hhf = hseg >> 5, hsub = hseg & 31;
    float lF = 0.f;
#pragma unroll
    for (int kff = 0; kff < 8; ++kff) lF += Lm[(qgf + 2 * kff) * 32 + qq];
    float4 a = {0.f, 0.f, 0.f, 0.f};
#pragma unroll
    for (int k2 = 0; k2 < 4; ++k2) {
      const float* Ob = OTm + (((qgf * 2 + hhf) * 4 + k2) << 10) + qq * 32 + hsub;
      float4 u = *(const float4*)Ob;
      a.x += u.x; a.y += u.y; a.z += u.z; a.w += u.w;
    }
    const float inv = 1.f / lF;
    a.x *= inv; a.y *= inv; a.z *= inv; a.w *= inv;
    *(float4*)(out + (b * SEQ + q0 + q) * HS + hseg) = a;
  }
}

// ---------------------------------------------------------------------------
extern "C" void kernel_launch(void* const* d_in, const int* in_sizes, int n_in,
                              void* d_out, int out_size, void* d_ws,
                              size_t ws_size, hipStream_t stream) {
  const float* x  = (const float*)d_in[0];
  const float* Wk = (const float*)d_in[1];
  const float* Wq = (const float*)d_in[2];
  const float* Wv = (const float*)d_in[3];
  float* out = (float*)d_out;

  unsigned short* us = (unsigned short*)d_ws;
  unsigned short* qh = us + 0 * (1 << 20);   // [B][N][H] bf16 hi
  unsigned short* ql = us + 1 * (1 << 20);   // [B][N][H] bf16 lo
  unsigned short* kh = us + 2 * (1 << 20);
  unsigned short* kl = us + 3 * (1 << 20);
  unsigned short* vt = us + 4 * (1 << 20);   // [B][H][N] bf16
  unsigned short* Wh = us + 5 * (1 << 20);   // [192][1024] bf16 hi
  unsigned short* Wl = Wh + 192 * 1024;      // [192][1024] bf16 lo

  wprep<<<192, 256, 0, stream>>>(Wk, Wq, Wv, Wh, Wl);
  qkv_x1<<<1024, 256, 0, stream>>>(x, Wh, Wl, qh, ql, kh, kl, vt);
  attn_mfma<<<dim3(64, NB), 1024, 0, stream>>>(qh, ql, kh, kl, vt, out);
}

// Round 10
// 188.046 us; speedup vs baseline: 1.1235x; 1.1235x over previous
//
#include <hip/hip_runtime.h>

#define NB   4
#define SEQ  4096
#define EMB  1024
#define HS   64

typedef __attribute__((ext_vector_type(8))) short bf16x8;   // 8 bf16 = 4 VGPRs
typedef __attribute__((ext_vector_type(4))) float f32x4;    // MFMA C/D

__device__ inline unsigned short f2bf(float f) {  // fp32 -> bf16 RNE
  unsigned int u = __float_as_uint(f);
  u += 0x7fffu + ((u >> 16) & 1u);
  return (unsigned short)(u >> 16);
}
__device__ inline float bf2f(unsigned short h) {
  return __uint_as_float(((unsigned int)h) << 16);
}
// 16B-chunk index in a [row][64] bf16 LDS tile, XOR-swizzled over row&7.
__device__ inline int swzi64(int row, int c) {
  return row * 64 + ((c ^ (row & 7)) << 3);
}
// same for [row][32] tiles (4 chunks/row, swizzle over (row>>1)&3)
__device__ inline int swzi32(int row, int c) {
  return row * 32 + ((c ^ ((row >> 1) & 3)) << 3);
}
// [row][128] tiles (16 chunks/row, swizzle over row&7)
__device__ inline int swzi128(int row, int c) {
  return row * 128 + ((c ^ (row & 7)) << 3);
}
// Async global->LDS 16B. LDS dest wave-uniform; lane i lands at +16*i.
__device__ inline void gld16(const unsigned short* g, unsigned short* l) {
  __builtin_amdgcn_global_load_lds(
      (const __attribute__((address_space(1))) void*)g,
      (__attribute__((address_space(3))) void*)l, 16, 0, 0);
}

// ---------------------------------------------------------------------------
// W prep: split Wq*scale*log2e | Wk | Wv into bf16 hi/lo [192][1024].
// ---------------------------------------------------------------------------
__global__ __launch_bounds__(256) void wprep(
    const float* __restrict__ Wk, const float* __restrict__ Wq,
    const float* __restrict__ Wv,
    unsigned short* __restrict__ Wh, unsigned short* __restrict__ Wl) {
  int i = blockIdx.x * 256 + threadIdx.x;  // float4 id, 192*1024/4 = 49152
  int e = i >> 8, c = i & 255;
  float4 v;
  float sc = 1.0f;
  if (e < 64)       { v = ((const float4*)Wq)[e * 256 + c];
                      sc = 0.18033688011112042f; }  // (1/sqrt(64))*log2(e)
  else if (e < 128)   v = ((const float4*)Wk)[(e - 64) * 256 + c];
  else                v = ((const float4*)Wv)[(e - 128) * 256 + c];
  v.x *= sc; v.y *= sc; v.z *= sc; v.w *= sc;
  ushort4 hv, lv;
  hv.x = f2bf(v.x); lv.x = f2bf(v.x - bf2f(hv.x));
  hv.y = f2bf(v.y); lv.y = f2bf(v.y - bf2f(hv.y));
  hv.z = f2bf(v.z); lv.z = f2bf(v.z - bf2f(hv.z));
  hv.w = f2bf(v.w); lv.w = f2bf(v.w - bf2f(hv.w));
  *(ushort4*)&Wh[i * 4] = hv;
  *(ushort4*)&Wl[i * 4] = lv;
}

// ---------------------------------------------------------------------------
// Single-pass fused QKV GEMM, round 10: r2 pipeline at 8 WAVES (512 thr).
// Lesson from r8 (attn win) vs r9 (qkv fail): more waves IN THE SAME BLOCK
// (finer split of the same step) helps; more blocks does not. Same m-tile
// 32, grid 512, LDS 56KB (2 blocks/CU) -> 16 waves/CU = 4 waves/SIMD.
// Wave (mi=w&1, ng=w>>1): rows 16mi..+15 x cols 48ng..+47 -> 9 MFMA +
// 8 ds_read/step (was 18+10). W staging: BOTH mi-waves of an ng-pair issue
// IDENTICAL gld16s (same bytes -> overlapping writes benign; each wave's
// own copies are ordered by its px-use counted vmcnt -> self-staging
// property preserved; partner's in-flight copy carries identical data).
// Loop barrier = raw lgkmcnt(0)+s_barrier, NO vmcnt drain (r2 scheme).
// ---------------------------------------------------------------------------
#define XhSp(p) ((unsigned short*)(SM + (p) * 2048))
#define XlSp(p) ((unsigned short*)(SM + 4096 + (p) * 2048))
#define WhSp(p) ((unsigned short*)(SM + 8192 + (p) * 12288))
#define WlSp(p) ((unsigned short*)(SM + 32768 + (p) * 12288))

__global__ __launch_bounds__(512) void qkv_x1(
    const float* __restrict__ x,
    const unsigned short* __restrict__ Wh, const unsigned short* __restrict__ Wl,
    unsigned short* __restrict__ qh, unsigned short* __restrict__ ql,
    unsigned short* __restrict__ kh, unsigned short* __restrict__ kl,
    unsigned short* __restrict__ vt) {
  __shared__ __align__(16) unsigned char SM[57344];

  const int t  = threadIdx.x;
  const int l  = t & 63;
  const int li = l & 15;
  const int g  = l >> 4;
  const int w  = t >> 6;         // 0..7
  const int mi = w & 1;          // row half 0/1
  const int ng = w >> 1;         // col group 0..3
  const int m0 = blockIdx.x * 32;
  const int b  = m0 >> 12;
  const int n0 = m0 & 4095;

  // x load/convert map: thread -> one float2 of the 32x32 tile
  const int xrow = t >> 4;       // 0..31
  const int c2   = t & 15;       // float-pair index, 16 per row
  const float* xp = x + (m0 + xrow) * EMB + 2 * c2;
  const int xaddr = xrow * 32 + (((c2 >> 2) ^ ((xrow >> 1) & 3)) << 3)
                    + (c2 & 3) * 2;

  // W gld16 lane-constant (seg = 16 W-rows x 32 k = 1KB)
  const int wconst = (l >> 2) * EMB + (((l & 3) ^ ((l >> 3) & 3)) << 3);

  f32x4 acc[3];
#pragma unroll
  for (int j = 0; j < 3; ++j) acc[j] = (f32x4){0.f, 0.f, 0.f, 0.f};

  const int rA  = 16 * mi + li;
  const int rB0 = 48 * ng + li, rB1 = rB0 + 16, rB2 = rB0 + 32;

  // Both mi-waves of an ng-pair issue the SAME 6 segs (duplicate, benign).
  auto issueW = [&](int s, int p) {
    const int ko = s * 32;
#pragma unroll
    for (int i = 0; i < 3; ++i) {
      const int seg = 3 * ng + i;
      gld16(Wh + 16 * seg * EMB + wconst + ko, WhSp(p) + seg * 512);
      gld16(Wl + 16 * seg * EMB + wconst + ko, WlSp(p) + seg * 512);
    }
  };
  auto writeX = [&](float2 v, int p) {
    unsigned short h0 = f2bf(v.x), h1 = f2bf(v.y);
    unsigned short e0 = f2bf(v.x - bf2f(h0)), e1 = f2bf(v.y - bf2f(h1));
    *(unsigned*)&XhSp(p)[xaddr] = (unsigned)h0 | ((unsigned)h1 << 16);
    *(unsigned*)&XlSp(p)[xaddr] = (unsigned)e0 | ((unsigned)e1 << 16);
  };

  float2 px = *(const float2*)xp;     // stage 0
  issueW(0, 0);
  writeX(px, 0);
  px = *(const float2*)(xp + 32);     // stage 1
  __syncthreads();                    // full drain ONCE: W(0)+x(0) landed

  for (int s = 0; s < 32; ++s) {
    const int p = s & 1;
    if (s < 31) {
      issueW(s + 1, p ^ 1);           // 6 gld16 -- fly across the barrier
      writeX(px, p ^ 1);              // px-use waits vmcnt(6): W(s) landed
      if (s < 30) px = *(const float2*)(xp + (s + 2) * 32);
    } else {
      asm volatile("s_waitcnt vmcnt(0)" ::: "memory");  // tail: W(31) landed
    }
    __builtin_amdgcn_sched_barrier(0);  // ds_reads must stay below the waits

    bf16x8 ah  = *(const bf16x8*)&XhSp(p)[swzi32(rA, g)];
    bf16x8 al  = *(const bf16x8*)&XlSp(p)[swzi32(rA, g)];
    bf16x8 bh0 = *(const bf16x8*)&WhSp(p)[swzi32(rB0, g)];
    bf16x8 bh1 = *(const bf16x8*)&WhSp(p)[swzi32(rB1, g)];
    bf16x8 bh2 = *(const bf16x8*)&WhSp(p)[swzi32(rB2, g)];
    bf16x8 bl0 = *(const bf16x8*)&WlSp(p)[swzi32(rB0, g)];
    bf16x8 bl1 = *(const bf16x8*)&WlSp(p)[swzi32(rB1, g)];
    bf16x8 bl2 = *(const bf16x8*)&WlSp(p)[swzi32(rB2, g)];

    __builtin_amdgcn_s_setprio(1);
    acc[0] = __builtin_amdgcn_mfma_f32_16x16x32_bf16(ah, bh0, acc[0], 0,0,0);
    acc[0] = __builtin_amdgcn_mfma_f32_16x16x32_bf16(ah, bl0, acc[0], 0,0,0);
    acc[0] = __builtin_amdgcn_mfma_f32_16x16x32_bf16(al, bh0, acc[0], 0,0,0);
    acc[1] = __builtin_amdgcn_mfma_f32_16x16x32_bf16(ah, bh1, acc[1], 0,0,0);
    acc[1] = __builtin_amdgcn_mfma_f32_16x16x32_bf16(ah, bl1, acc[1], 0,0,0);
    acc[1] = __builtin_amdgcn_mfma_f32_16x16x32_bf16(al, bh1, acc[1], 0,0,0);
    acc[2] = __builtin_amdgcn_mfma_f32_16x16x32_bf16(ah, bh2, acc[2], 0,0,0);
    acc[2] = __builtin_amdgcn_mfma_f32_16x16x32_bf16(ah, bl2, acc[2], 0,0,0);
    acc[2] = __builtin_amdgcn_mfma_f32_16x16x32_bf16(al, bh2, acc[2], 0,0,0);
    __builtin_amdgcn_s_setprio(0);

    // Raw barrier: X(s+1) ds_writes visible (lgkmcnt) WITHOUT draining the
    // in-flight W(s+1)/px vmem ops.
    asm volatile("s_waitcnt lgkmcnt(0)" ::: "memory");
    __builtin_amdgcn_s_barrier();
    __builtin_amdgcn_sched_barrier(0);
  }

  // Epilogue: D[m=16mi+4g+r][n=48ng+16j+li]
#pragma unroll
  for (int j = 0; j < 3; ++j) {
    const int H3 = 48 * ng + 16 * j + li;
#pragma unroll
    for (int r = 0; r < 4; ++r) {
      const int mrow = 16 * mi + 4 * g + r;
      const float vv = acc[j][r];
      if (H3 < 64) {
        const unsigned short hb = f2bf(vv);
        const int off = (b * SEQ + n0 + mrow) * HS + H3;
        qh[off] = hb; ql[off] = f2bf(vv - bf2f(hb));
      } else if (H3 < 128) {
        const unsigned short hb = f2bf(vv);
        const int off = (b * SEQ + n0 + mrow) * HS + (H3 - 64);
        kh[off] = hb; kl[off] = f2bf(vv - bf2f(hb));
      } else {
        vt[(b * HS + (H3 - 128)) * SEQ + n0 + mrow] = f2bf(vv);
      }
    }
  }
}

// ---------------------------------------------------------------------------
// Flash attention, round-8 structure (best): 16 waves (1024 thr) = 4
// waves/SIMD. QK wave (qg=w&1, kf=w>>1): 32q x 16 keys; PV wave (qg, ks2,
// hh): 32q x 32keys x 32h. Deferred PV (T15), V 3-buf, Pt 2 time-parities,
// one barrier/iter. UNCHANGED this round.
// ---------------------------------------------------------------------------
__global__ __launch_bounds__(1024) void attn_mfma(
    const unsigned short* __restrict__ qh, const unsigned short* __restrict__ ql,
    const unsigned short* __restrict__ kh, const unsigned short* __restrict__ kl,
    const unsigned short* __restrict__ vt, float* __restrict__ out) {
  __shared__ __align__(16) unsigned char SM[155648];
  // layout: Kh[p] @ p*16384 (2x16KB)           [0 .. 32K)
  //         Kl[p] @ 32768 + p*16384 (2x16KB)   [32K .. 64K)
  //         Vt[v] @ 65536 + v*16384 (3x16KB)   [64K .. 112K)
  //         Pt    @ 114688, 8 slabs x 2 time-parities x 1280 ush (40KB)
  unsigned short* const PtS = (unsigned short*)(SM + 114688);

  const int t  = threadIdx.x;
  const int l  = t & 63;
  const int li = l & 15;
  const int g  = l >> 4;
  const int w  = t >> 6;        // 0..15
  const int qg = w & 1;         // QK role: q-half
  const int kf = w >> 1;        // QK role: 16-key group 0..7
  const int ks2 = (w >> 1) & 3; // PV role: 32-key slice
  const int hh  = w >> 3;       // PV role: 32-h half
  const int b  = blockIdx.y;
  const int q0 = blockIdx.x << 6;

  // Persistent Q fragments, 2 q-sets (B[k=h][n=q], n=li), rows 32qg+16qs+li.
  bf16x8 qfh[2][2], qfl[2][2];
#pragma unroll
  for (int qs = 0; qs < 2; ++qs) {
    const unsigned short* qrh = qh + (b * SEQ + q0 + 32 * qg + 16 * qs + li) * HS;
    const unsigned short* qrl = ql + (b * SEQ + q0 + 32 * qg + 16 * qs + li) * HS;
    qfh[qs][0] = *(const bf16x8*)&qrh[8 * g];
    qfh[qs][1] = *(const bf16x8*)&qrh[32 + 8 * g];
    qfl[qs][0] = *(const bf16x8*)&qrl[8 * g];
    qfl[qs][1] = *(const bf16x8*)&qrl[32 + 8 * g];
  }

  // gld16 lane constants. K segs: 8 key-rows x 64 h = 1KB; seg = w.
  const int kconst = (l >> 3) * HS + (((l & 7) ^ (l >> 3)) << 3);
  // V segs: 4 h-rows x 128 keys = 1KB; chunk perm depends on seg parity.
  const int rowl = l >> 4, slot = l & 15;
  const int vc = (w & 1) ? rowl * SEQ + ((slot ^ (4 + rowl)) << 3)
                         : rowl * SEQ + ((slot ^ rowl) << 3);
  const unsigned short* khB = kh + b * SEQ * HS;
  const unsigned short* klB = kl + b * SEQ * HS;
  const unsigned short* vtB = vt + b * HS * SEQ;

  f32x4 O[2][2];                // [ht2][qs-of-pg]
#pragma unroll
  for (int i = 0; i < 2; ++i) {
    O[i][0] = (f32x4){0.f, 0.f, 0.f, 0.f};
    O[i][1] = (f32x4){0.f, 0.f, 0.f, 0.f};
  }
  float lp0 = 0.f, lp1 = 0.f;

  // Pt write constants: slab = qg + 2*(kf>>1); chunk c = 2*(kf&1) + (g>>1).
  const int slabW = qg + 2 * (kf >> 1);
  const int cW = 2 * (kf & 1) + (g >> 1);
  const int subW = (g & 1) << 2;

  auto stage = [&](int it, int pK, int vb) {
    const int kt0 = it << 7;  // 128 keys per tile
    unsigned short* const KhP = (unsigned short*)(SM + pK * 16384);
    unsigned short* const KlP = (unsigned short*)(SM + 32768 + pK * 16384);
    unsigned short* const VtP = (unsigned short*)(SM + 65536 + vb * 16384);
    gld16(khB + (kt0 + 8 * w) * HS + kconst, KhP + w * 512);
    gld16(klB + (kt0 + 8 * w) * HS + kconst, KlP + w * 512);
    gld16(vtB + 4 * w * SEQ + kt0 + vc, VtP + w * 512);
  };

  // PV of a prior tile: Pt time-parity `par`, V buffer `vb`.
  auto PV = [&](int par, int vb) {
    unsigned short* const PtP = PtS + (qg + 2 * ks2) * 2560 + par * 1280;
    unsigned short* const VtP = (unsigned short*)(SM + 65536 + vb * 16384);
    bf16x8 pb0 = *(const bf16x8*)&PtP[li * 40 + ((g ^ (li & 3)) << 3)];
    const int r1 = 16 + li;
    bf16x8 pb1 = *(const bf16x8*)&PtP[r1 * 40 + ((g ^ (r1 & 3)) << 3)];
    __builtin_amdgcn_s_setprio(1);
#pragma unroll
    for (int ht2 = 0; ht2 < 2; ++ht2) {
      const int vrow = 32 * hh + 16 * ht2 + li;
      bf16x8 va = *(const bf16x8*)&VtP[swzi128(vrow, 4 * ks2 + g)];
      O[ht2][0] = __builtin_amdgcn_mfma_f32_16x16x32_bf16(va, pb0, O[ht2][0], 0,0,0);
      O[ht2][1] = __builtin_amdgcn_mfma_f32_16x16x32_bf16(va, pb1, O[ht2][1], 0,0,0);
    }
    __builtin_amdgcn_s_setprio(0);
  };

  stage(0, 0, 0);
  __syncthreads();            // drains tile 0 -> K[0], V[0] ready

  int vbn = 1;                // (it+1)%3
  int vbp = 2;                // (it-1)%3 (unused at it=0)
  for (int it = 0; it < 32; ++it) {
    const int p = it & 1;
    if (it < 31) stage(it + 1, p ^ 1, vbn);  // flies during compute of tile it

    unsigned short* const KhS = (unsigned short*)(SM + p * 16384);
    unsigned short* const KlS = (unsigned short*)(SM + 32768 + p * 16384);

    // QK^T(it): this wave's 16 keys (16kf + 4g + r) x its 32 q.
    f32x4 S[2];
    S[0] = (f32x4){-32.f, -32.f, -32.f, -32.f};
    S[1] = (f32x4){-32.f, -32.f, -32.f, -32.f};
    __builtin_amdgcn_s_setprio(1);
#pragma unroll
    for (int khf = 0; khf < 2; ++khf) {
      const int row = 16 * kf + li;
      bf16x8 akh = *(const bf16x8*)&KhS[swzi64(row, 4 * khf + g)];
      bf16x8 akl = *(const bf16x8*)&KlS[swzi64(row, 4 * khf + g)];
      S[0] = __builtin_amdgcn_mfma_f32_16x16x32_bf16(akh, qfh[0][khf], S[0], 0,0,0);
      S[0] = __builtin_amdgcn_mfma_f32_16x16x32_bf16(akh, qfl[0][khf], S[0], 0,0,0);
      S[0] = __builtin_amdgcn_mfma_f32_16x16x32_bf16(akl, qfh[0][khf], S[0], 0,0,0);
      S[1] = __builtin_amdgcn_mfma_f32_16x16x32_bf16(akh, qfh[1][khf], S[1], 0,0,0);
      S[1] = __builtin_amdgcn_mfma_f32_16x16x32_bf16(akh, qfl[1][khf], S[1], 0,0,0);
      S[1] = __builtin_amdgcn_mfma_f32_16x16x32_bf16(akl, qfh[1][khf], S[1], 0,0,0);
    }
    __builtin_amdgcn_s_setprio(0);

    // PV of PREVIOUS tile (other time-parity Pt + V[vbp]); independent of
    // S(it) -> overlaps the exp chain below.
    if (it > 0) PV(p ^ 1, vbp);

    // exp2, truncate to bf16, write Pt (parity p), accumulate l.
#pragma unroll
    for (int qs = 0; qs < 2; ++qs) {
      unsigned pu[4];
      float ls = 0.f;
#pragma unroll
      for (int r = 0; r < 4; ++r) {
        const float pe = exp2f(S[qs][r]);
        pu[r] = __float_as_uint(pe);
        ls += __uint_as_float(pu[r] & 0xffff0000u);
      }
      if (qs == 0) lp0 += ls; else lp1 += ls;
      const unsigned p01 = __builtin_amdgcn_perm(pu[1], pu[0], 0x07060302u);
      const unsigned p23 = __builtin_amdgcn_perm(pu[3], pu[2], 0x07060302u);
      const int qrow = 16 * qs + li;
      const int addr = qrow * 40 + (((cW ^ (qrow & 3))) << 3) + subW;
      int2 pv; pv.x = (int)p01; pv.y = (int)p23;
      *(int2*)&PtS[slabW * 2560 + p * 1280 + addr] = pv;
    }

    // ONE barrier/iter: drains tile it+1 staging + orders Pt/V/K reuse.
    __syncthreads();

    vbn = (vbn == 2) ? 0 : vbn + 1;
    vbp = (vbp == 2) ? 0 : vbp + 1;
  }

  // Drain: PV of tile 31 (Pt parity 1, V[31%3=1]).
  PV(1, 1);

  // reduce l over g (wave's 16 keys spread over g-quads)
  lp0 += __shfl_xor(lp0, 16); lp0 += __shfl_xor(lp0, 32);
  lp1 += __shfl_xor(lp1, 16); lp1 += __shfl_xor(lp1, 32);

  // Merge. OTm [0,64K) = K buffers (consumed); Lm 2KB in V[0] (not read by
  // PV(31), which reads V[1]+Pt) -- disjoint, no extra barrier needed.
  float* const OTm = (float*)SM;               // 16 x [32q][32h] f32 = 64KB
  float* const Lm  = (float*)(SM + 65536);     // [16 qk-waves][32 q]
#pragma unroll
  for (int ht2 = 0; ht2 < 2; ++ht2)
#pragma unroll
    for (int qs = 0; qs < 2; ++qs) {
      float4 o4;
      o4.x = O[ht2][qs][0]; o4.y = O[ht2][qs][1];
      o4.z = O[ht2][qs][2]; o4.w = O[ht2][qs][3];
      // sub-array id: (pg*2 + hh)*4 + ks2 ; within: [16qs+li][32h]
      *(float4*)&OTm[(((qg * 2 + hh) * 4 + ks2) << 10)
                     + (16 * qs + li) * 32 + 16 * ht2 + 4 * g] = o4;
    }
  if (g == 0) { Lm[w * 32 + li] = lp0; Lm[w * 32 + 16 + li] = lp1; }
  __syncthreads();

  // final: thread t -> q = t>>4 (64), hseg = (t&15)*4; sum 4 key-slices.
  {
    const int q = t >> 4, hseg = (t & 15) << 2;
    const int qq = q & 31, qgf = q >> 5;
    const int hhf = hseg >> 5, hsub = hseg & 31;
    float lF = 0.f;
#pragma unroll
    for (int kff = 0; kff < 8; ++kff) lF += Lm[(qgf + 2 * kff) * 32 + qq];
    float4 a = {0.f, 0.f, 0.f, 0.f};
#pragma unroll
    for (int k2 = 0; k2 < 4; ++k2) {
      const float* Ob = OTm + (((qgf * 2 + hhf) * 4 + k2) << 10) + qq * 32 + hsub;
      float4 u = *(const float4*)Ob;
      a.x += u.x; a.y += u.y; a.z += u.z; a.w += u.w;
    }
    const float inv = 1.f / lF;
    a.x *= inv; a.y *= inv; a.z *= inv; a.w *= inv;
    *(float4*)(out + (b * SEQ + q0 + q) * HS + hseg) = a;
  }
}

// ---------------------------------------------------------------------------
extern "C" void kernel_launch(void* const* d_in, const int* in_sizes, int n_in,
                              void* d_out, int out_size, void* d_ws,
                              size_t ws_size, hipStream_t stream) {
  const float* x  = (const float*)d_in[0];
  const float* Wk = (const float*)d_in[1];
  const float* Wq = (const float*)d_in[2];
  const float* Wv = (const float*)d_in[3];
  float* out = (float*)d_out;

  unsigned short* us = (unsigned short*)d_ws;
  unsigned short* qh = us + 0 * (1 << 20);   // [B][N][H] bf16 hi
  unsigned short* ql = us + 1 * (1 << 20);   // [B][N][H] bf16 lo
  unsigned short* kh = us + 2 * (1 << 20);
  unsigned short* kl = us + 3 * (1 << 20);
  unsigned short* vt = us + 4 * (1 << 20);   // [B][H][N] bf16
  unsigned short* Wh = us + 5 * (1 << 20);   // [192][1024] bf16 hi
  unsigned short* Wl = Wh + 192 * 1024;      // [192][1024] bf16 lo

  wprep<<<192, 256, 0, stream>>>(Wk, Wq, Wv, Wh, Wl);
  qkv_x1<<<512, 512, 0, stream>>>(x, Wh, Wl, qh, ql, kh, kl, vt);
  attn_mfma<<<dim3(64, NB), 1024, 0, stream>>>(qh, ql, kh, kl, vt, out);
}

// Round 11
// 182.763 us; speedup vs baseline: 1.1560x; 1.0289x over previous
//
#include <hip/hip_runtime.h>

#define NB   4
#define SEQ  4096
#define EMB  1024
#define HS   64

typedef __attribute__((ext_vector_type(8))) short bf16x8;   // 8 bf16 = 4 VGPRs
typedef __attribute__((ext_vector_type(4))) float f32x4;    // MFMA C/D

__device__ inline unsigned short f2bf(float f) {  // fp32 -> bf16 RNE
  unsigned int u = __float_as_uint(f);
  u += 0x7fffu + ((u >> 16) & 1u);
  return (unsigned short)(u >> 16);
}
__device__ inline float bf2f(unsigned short h) {
  return __uint_as_float(((unsigned int)h) << 16);
}
// 16B-chunk index in a [row][64] bf16 LDS tile, XOR-swizzled over row&7.
__device__ inline int swzi64(int row, int c) {
  return row * 64 + ((c ^ (row & 7)) << 3);
}
// same for [row][32] tiles (4 chunks/row, swizzle over (row>>1)&3)
__device__ inline int swzi32(int row, int c) {
  return row * 32 + ((c ^ ((row >> 1) & 3)) << 3);
}
// [row][128] tiles (16 chunks/row, swizzle over row&7)
__device__ inline int swzi128(int row, int c) {
  return row * 128 + ((c ^ (row & 7)) << 3);
}
// Async global->LDS 16B. LDS dest wave-uniform; lane i lands at +16*i.
__device__ inline void gld16(const unsigned short* g, unsigned short* l) {
  __builtin_amdgcn_global_load_lds(
      (const __attribute__((address_space(1))) void*)g,
      (__attribute__((address_space(3))) void*)l, 16, 0, 0);
}

// ---------------------------------------------------------------------------
// W prep: split Wq*scale*log2e | Wk | Wv into bf16 hi/lo [192][1024].
// ---------------------------------------------------------------------------
__global__ __launch_bounds__(256) void wprep(
    const float* __restrict__ Wk, const float* __restrict__ Wq,
    const float* __restrict__ Wv,
    unsigned short* __restrict__ Wh, unsigned short* __restrict__ Wl) {
  int i = blockIdx.x * 256 + threadIdx.x;  // float4 id, 192*1024/4 = 49152
  int e = i >> 8, c = i & 255;
  float4 v;
  float sc = 1.0f;
  if (e < 64)       { v = ((const float4*)Wq)[e * 256 + c];
                      sc = 0.18033688011112042f; }  // (1/sqrt(64))*log2(e)
  else if (e < 128)   v = ((const float4*)Wk)[(e - 64) * 256 + c];
  else                v = ((const float4*)Wv)[(e - 128) * 256 + c];
  v.x *= sc; v.y *= sc; v.z *= sc; v.w *= sc;
  ushort4 hv, lv;
  hv.x = f2bf(v.x); lv.x = f2bf(v.x - bf2f(hv.x));
  hv.y = f2bf(v.y); lv.y = f2bf(v.y - bf2f(hv.y));
  hv.z = f2bf(v.z); lv.z = f2bf(v.z - bf2f(hv.z));
  hv.w = f2bf(v.w); lv.w = f2bf(v.w - bf2f(hv.w));
  *(ushort4*)&Wh[i * 4] = hv;
  *(ushort4*)&Wl[i * 4] = lv;
}

// ---------------------------------------------------------------------------
// Single-pass fused QKV GEMM, round 11: 8 waves (512 thr), DEDUPED staging.
// r10 analysis: its regression vs r2 was the duplicated gld16s (96 KB vs
// 48 KB of W per CU per step). Fix: only the mi=0 wave of each ng-pair
// stages W (24 gld16/block/step, byte-identical to r2). Ordering moves to
// the barrier via stage-early/drain-late: issueW(s+1) at TOP of step s,
// `s_waitcnt vmcnt(1)` (W landed, px may fly) at END before s_barrier --
// the W loads get the whole step's compute to land (attn-r1 pattern).
// Consumers hold only px -> vmcnt(1) free. Tail steps use vmcnt(0).
// Per-wave step: 9 MFMA + 8 ds_read (half of r2) at 4 waves/SIMD (2x r2).
// ---------------------------------------------------------------------------
#define XhSp(p) ((unsigned short*)(SM + (p) * 2048))
#define XlSp(p) ((unsigned short*)(SM + 4096 + (p) * 2048))
#define WhSp(p) ((unsigned short*)(SM + 8192 + (p) * 12288))
#define WlSp(p) ((unsigned short*)(SM + 32768 + (p) * 12288))

__global__ __launch_bounds__(512) void qkv_x1(
    const float* __restrict__ x,
    const unsigned short* __restrict__ Wh, const unsigned short* __restrict__ Wl,
    unsigned short* __restrict__ qh, unsigned short* __restrict__ ql,
    unsigned short* __restrict__ kh, unsigned short* __restrict__ kl,
    unsigned short* __restrict__ vt) {
  __shared__ __align__(16) unsigned char SM[57344];

  const int t  = threadIdx.x;
  const int l  = t & 63;
  const int li = l & 15;
  const int g  = l >> 4;
  const int w  = t >> 6;         // 0..7
  const int mi = w & 1;          // row half 0/1
  const int ng = w >> 1;         // col group 0..3
  const int m0 = blockIdx.x * 32;
  const int b  = m0 >> 12;
  const int n0 = m0 & 4095;

  // x load/convert map: thread -> one float2 of the 32x32 tile
  const int xrow = t >> 4;       // 0..31
  const int c2   = t & 15;       // float-pair index, 16 per row
  const float* xp = x + (m0 + xrow) * EMB + 2 * c2;
  const int xaddr = xrow * 32 + (((c2 >> 2) ^ ((xrow >> 1) & 3)) << 3)
                    + (c2 & 3) * 2;

  // W gld16 lane-constant (seg = 16 W-rows x 32 k = 1KB)
  const int wconst = (l >> 2) * EMB + (((l & 3) ^ ((l >> 3) & 3)) << 3);

  f32x4 acc[3];
#pragma unroll
  for (int j = 0; j < 3; ++j) acc[j] = (f32x4){0.f, 0.f, 0.f, 0.f};

  const int rA  = 16 * mi + li;
  const int rB0 = 48 * ng + li, rB1 = rB0 + 16, rB2 = rB0 + 32;

  // ONLY mi=0 waves stage W (dedup -- r10's regression was 2x W bytes).
  auto issueW = [&](int s, int p) {
    if (mi == 0) {
      const int ko = s * 32;
#pragma unroll
      for (int i = 0; i < 3; ++i) {
        const int seg = 3 * ng + i;
        gld16(Wh + 16 * seg * EMB + wconst + ko, WhSp(p) + seg * 512);
        gld16(Wl + 16 * seg * EMB + wconst + ko, WlSp(p) + seg * 512);
      }
    }
  };
  auto writeX = [&](float2 v, int p) {
    unsigned short h0 = f2bf(v.x), h1 = f2bf(v.y);
    unsigned short e0 = f2bf(v.x - bf2f(h0)), e1 = f2bf(v.y - bf2f(h1));
    *(unsigned*)&XhSp(p)[xaddr] = (unsigned)h0 | ((unsigned)h1 << 16);
    *(unsigned*)&XlSp(p)[xaddr] = (unsigned)e0 | ((unsigned)e1 << 16);
  };

  float2 px = *(const float2*)xp;     // stage 0
  issueW(0, 0);
  writeX(px, 0);
  px = *(const float2*)(xp + 32);     // stage 1
  __syncthreads();                    // full drain ONCE: W(0)+x(0) landed

  for (int s = 0; s < 32; ++s) {
    const int p = s & 1;
    if (s < 31) {
      issueW(s + 1, p ^ 1);           // issued at TOP -> whole step to land
      writeX(px, p ^ 1);
      if (s < 30) px = *(const float2*)(xp + (s + 2) * 32);
    }

    bf16x8 ah  = *(const bf16x8*)&XhSp(p)[swzi32(rA, g)];
    bf16x8 al  = *(const bf16x8*)&XlSp(p)[swzi32(rA, g)];
    bf16x8 bh0 = *(const bf16x8*)&WhSp(p)[swzi32(rB0, g)];
    bf16x8 bh1 = *(const bf16x8*)&WhSp(p)[swzi32(rB1, g)];
    bf16x8 bh2 = *(const bf16x8*)&WhSp(p)[swzi32(rB2, g)];
    bf16x8 bl0 = *(const bf16x8*)&WlSp(p)[swzi32(rB0, g)];
    bf16x8 bl1 = *(const bf16x8*)&WlSp(p)[swzi32(rB1, g)];
    bf16x8 bl2 = *(const bf16x8*)&WlSp(p)[swzi32(rB2, g)];

    __builtin_amdgcn_s_setprio(1);
    acc[0] = __builtin_amdgcn_mfma_f32_16x16x32_bf16(ah, bh0, acc[0], 0,0,0);
    acc[0] = __builtin_amdgcn_mfma_f32_16x16x32_bf16(ah, bl0, acc[0], 0,0,0);
    acc[0] = __builtin_amdgcn_mfma_f32_16x16x32_bf16(al, bh0, acc[0], 0,0,0);
    acc[1] = __builtin_amdgcn_mfma_f32_16x16x32_bf16(ah, bh1, acc[1], 0,0,0);
    acc[1] = __builtin_amdgcn_mfma_f32_16x16x32_bf16(ah, bl1, acc[1], 0,0,0);
    acc[1] = __builtin_amdgcn_mfma_f32_16x16x32_bf16(al, bh1, acc[1], 0,0,0);
    acc[2] = __builtin_amdgcn_mfma_f32_16x16x32_bf16(ah, bh2, acc[2], 0,0,0);
    acc[2] = __builtin_amdgcn_mfma_f32_16x16x32_bf16(ah, bl2, acc[2], 0,0,0);
    acc[2] = __builtin_amdgcn_mfma_f32_16x16x32_bf16(al, bh2, acc[2], 0,0,0);
    __builtin_amdgcn_s_setprio(0);

    // Drain-late barrier: W(s+1) must have landed (issued at top of this
    // step -> ~full step of flight time). vmcnt(1) leaves px in flight;
    // consumers' queue holds only px so it's free for them. Tail steps
    // (no px outstanding guarantee) drain fully.
    if (s < 30) {
      asm volatile("s_waitcnt vmcnt(1) lgkmcnt(0)" ::: "memory");
    } else {
      asm volatile("s_waitcnt vmcnt(0) lgkmcnt(0)" ::: "memory");
    }
    __builtin_amdgcn_s_barrier();
    __builtin_amdgcn_sched_barrier(0);
  }

  // Epilogue: D[m=16mi+4g+r][n=48ng+16j+li]
#pragma unroll
  for (int j = 0; j < 3; ++j) {
    const int H3 = 48 * ng + 16 * j + li;
#pragma unroll
    for (int r = 0; r < 4; ++r) {
      const int mrow = 16 * mi + 4 * g + r;
      const float vv = acc[j][r];
      if (H3 < 64) {
        const unsigned short hb = f2bf(vv);
        const int off = (b * SEQ + n0 + mrow) * HS + H3;
        qh[off] = hb; ql[off] = f2bf(vv - bf2f(hb));
      } else if (H3 < 128) {
        const unsigned short hb = f2bf(vv);
        const int off = (b * SEQ + n0 + mrow) * HS + (H3 - 64);
        kh[off] = hb; kl[off] = f2bf(vv - bf2f(hb));
      } else {
        vt[(b * HS + (H3 - 128)) * SEQ + n0 + mrow] = f2bf(vv);
      }
    }
  }
}

// ---------------------------------------------------------------------------
// Flash attention, round-8 structure (best): 16 waves (1024 thr) = 4
// waves/SIMD. QK wave (qg=w&1, kf=w>>1): 32q x 16 keys; PV wave (qg, ks2,
// hh): 32q x 32keys x 32h. Deferred PV (T15), V 3-buf, Pt 2 time-parities,
// one barrier/iter. UNCHANGED this round.
// ---------------------------------------------------------------------------
__global__ __launch_bounds__(1024) void attn_mfma(
    const unsigned short* __restrict__ qh, const unsigned short* __restrict__ ql,
    const unsigned short* __restrict__ kh, const unsigned short* __restrict__ kl,
    const unsigned short* __restrict__ vt, float* __restrict__ out) {
  __shared__ __align__(16) unsigned char SM[155648];
  // layout: Kh[p] @ p*16384 (2x16KB)           [0 .. 32K)
  //         Kl[p] @ 32768 + p*16384 (2x16KB)   [32K .. 64K)
  //         Vt[v] @ 65536 + v*16384 (3x16KB)   [64K .. 112K)
  //         Pt    @ 114688, 8 slabs x 2 time-parities x 1280 ush (40KB)
  unsigned short* const PtS = (unsigned short*)(SM + 114688);

  const int t  = threadIdx.x;
  const int l  = t & 63;
  const int li = l & 15;
  const int g  = l >> 4;
  const int w  = t >> 6;        // 0..15
  const int qg = w & 1;         // QK role: q-half
  const int kf = w >> 1;        // QK role: 16-key group 0..7
  const int ks2 = (w >> 1) & 3; // PV role: 32-key slice
  const int hh  = w >> 3;       // PV role: 32-h half
  const int b  = blockIdx.y;
  const int q0 = blockIdx.x << 6;

  // Persistent Q fragments, 2 q-sets (B[k=h][n=q], n=li), rows 32qg+16qs+li.
  bf16x8 qfh[2][2], qfl[2][2];
#pragma unroll
  for (int qs = 0; qs < 2; ++qs) {
    const unsigned short* qrh = qh + (b * SEQ + q0 + 32 * qg + 16 * qs + li) * HS;
    const unsigned short* qrl = ql + (b * SEQ + q0 + 32 * qg + 16 * qs + li) * HS;
    qfh[qs][0] = *(const bf16x8*)&qrh[8 * g];
    qfh[qs][1] = *(const bf16x8*)&qrh[32 + 8 * g];
    qfl[qs][0] = *(const bf16x8*)&qrl[8 * g];
    qfl[qs][1] = *(const bf16x8*)&qrl[32 + 8 * g];
  }

  // gld16 lane constants. K segs: 8 key-rows x 64 h = 1KB; seg = w.
  const int kconst = (l >> 3) * HS + (((l & 7) ^ (l >> 3)) << 3);
  // V segs: 4 h-rows x 128 keys = 1KB; chunk perm depends on seg parity.
  const int rowl = l >> 4, slot = l & 15;
  const int vc = (w & 1) ? rowl * SEQ + ((slot ^ (4 + rowl)) << 3)
                         : rowl * SEQ + ((slot ^ rowl) << 3);
  const unsigned short* khB = kh + b * SEQ * HS;
  const unsigned short* klB = kl + b * SEQ * HS;
  const unsigned short* vtB = vt + b * HS * SEQ;

  f32x4 O[2][2];                // [ht2][qs-of-pg]
#pragma unroll
  for (int i = 0; i < 2; ++i) {
    O[i][0] = (f32x4){0.f, 0.f, 0.f, 0.f};
    O[i][1] = (f32x4){0.f, 0.f, 0.f, 0.f};
  }
  float lp0 = 0.f, lp1 = 0.f;

  // Pt write constants: slab = qg + 2*(kf>>1); chunk c = 2*(kf&1) + (g>>1).
  const int slabW = qg + 2 * (kf >> 1);
  const int cW = 2 * (kf & 1) + (g >> 1);
  const int subW = (g & 1) << 2;

  auto stage = [&](int it, int pK, int vb) {
    const int kt0 = it << 7;  // 128 keys per tile
    unsigned short* const KhP = (unsigned short*)(SM + pK * 16384);
    unsigned short* const KlP = (unsigned short*)(SM + 32768 + pK * 16384);
    unsigned short* const VtP = (unsigned short*)(SM + 65536 + vb * 16384);
    gld16(khB + (kt0 + 8 * w) * HS + kconst, KhP + w * 512);
    gld16(klB + (kt0 + 8 * w) * HS + kconst, KlP + w * 512);
    gld16(vtB + 4 * w * SEQ + kt0 + vc, VtP + w * 512);
  };

  // PV of a prior tile: Pt time-parity `par`, V buffer `vb`.
  auto PV = [&](int par, int vb) {
    unsigned short* const PtP = PtS + (qg + 2 * ks2) * 2560 + par * 1280;
    unsigned short* const VtP = (unsigned short*)(SM + 65536 + vb * 16384);
    bf16x8 pb0 = *(const bf16x8*)&PtP[li * 40 + ((g ^ (li & 3)) << 3)];
    const int r1 = 16 + li;
    bf16x8 pb1 = *(const bf16x8*)&PtP[r1 * 40 + ((g ^ (r1 & 3)) << 3)];
    __builtin_amdgcn_s_setprio(1);
#pragma unroll
    for (int ht2 = 0; ht2 < 2; ++ht2) {
      const int vrow = 32 * hh + 16 * ht2 + li;
      bf16x8 va = *(const bf16x8*)&VtP[swzi128(vrow, 4 * ks2 + g)];
      O[ht2][0] = __builtin_amdgcn_mfma_f32_16x16x32_bf16(va, pb0, O[ht2][0], 0,0,0);
      O[ht2][1] = __builtin_amdgcn_mfma_f32_16x16x32_bf16(va, pb1, O[ht2][1], 0,0,0);
    }
    __builtin_amdgcn_s_setprio(0);
  };

  stage(0, 0, 0);
  __syncthreads();            // drains tile 0 -> K[0], V[0] ready

  int vbn = 1;                // (it+1)%3
  int vbp = 2;                // (it-1)%3 (unused at it=0)
  for (int it = 0; it < 32; ++it) {
    const int p = it & 1;
    if (it < 31) stage(it + 1, p ^ 1, vbn);  // flies during compute of tile it

    unsigned short* const KhS = (unsigned short*)(SM + p * 16384);
    unsigned short* const KlS = (unsigned short*)(SM + 32768 + p * 16384);

    // QK^T(it): this wave's 16 keys (16kf + 4g + r) x its 32 q.
    f32x4 S[2];
    S[0] = (f32x4){-32.f, -32.f, -32.f, -32.f};
    S[1] = (f32x4){-32.f, -32.f, -32.f, -32.f};
    __builtin_amdgcn_s_setprio(1);
#pragma unroll
    for (int khf = 0; khf < 2; ++khf) {
      const int row = 16 * kf + li;
      bf16x8 akh = *(const bf16x8*)&KhS[swzi64(row, 4 * khf + g)];
      bf16x8 akl = *(const bf16x8*)&KlS[swzi64(row, 4 * khf + g)];
      S[0] = __builtin_amdgcn_mfma_f32_16x16x32_bf16(akh, qfh[0][khf], S[0], 0,0,0);
      S[0] = __builtin_amdgcn_mfma_f32_16x16x32_bf16(akh, qfl[0][khf], S[0], 0,0,0);
      S[0] = __builtin_amdgcn_mfma_f32_16x16x32_bf16(akl, qfh[0][khf], S[0], 0,0,0);
      S[1] = __builtin_amdgcn_mfma_f32_16x16x32_bf16(akh, qfh[1][khf], S[1], 0,0,0);
      S[1] = __builtin_amdgcn_mfma_f32_16x16x32_bf16(akh, qfl[1][khf], S[1], 0,0,0);
      S[1] = __builtin_amdgcn_mfma_f32_16x16x32_bf16(akl, qfh[1][khf], S[1], 0,0,0);
    }
    __builtin_amdgcn_s_setprio(0);

    // PV of PREVIOUS tile (other time-parity Pt + V[vbp]); independent of
    // S(it) -> overlaps the exp chain below.
    if (it > 0) PV(p ^ 1, vbp);

    // exp2, truncate to bf16, write Pt (parity p), accumulate l.
#pragma unroll
    for (int qs = 0; qs < 2; ++qs) {
      unsigned pu[4];
      float ls = 0.f;
#pragma unroll
      for (int r = 0; r < 4; ++r) {
        const float pe = exp2f(S[qs][r]);
        pu[r] = __float_as_uint(pe);
        ls += __uint_as_float(pu[r] & 0xffff0000u);
      }
      if (qs == 0) lp0 += ls; else lp1 += ls;
      const unsigned p01 = __builtin_amdgcn_perm(pu[1], pu[0], 0x07060302u);
      const unsigned p23 = __builtin_amdgcn_perm(pu[3], pu[2], 0x07060302u);
      const int qrow = 16 * qs + li;
      const int addr = qrow * 40 + (((cW ^ (qrow & 3))) << 3) + subW;
      int2 pv; pv.x = (int)p01; pv.y = (int)p23;
      *(int2*)&PtS[slabW * 2560 + p * 1280 + addr] = pv;
    }

    // ONE barrier/iter: drains tile it+1 staging + orders Pt/V/K reuse.
    __syncthreads();

    vbn = (vbn == 2) ? 0 : vbn + 1;
    vbp = (vbp == 2) ? 0 : vbp + 1;
  }

  // Drain: PV of tile 31 (Pt parity 1, V[31%3=1]).
  PV(1, 1);

  // reduce l over g (wave's 16 keys spread over g-quads)
  lp0 += __shfl_xor(lp0, 16); lp0 += __shfl_xor(lp0, 32);
  lp1 += __shfl_xor(lp1, 16); lp1 += __shfl_xor(lp1, 32);

  // Merge. OTm [0,64K) = K buffers (consumed); Lm 2KB in V[0] (not read by
  // PV(31), which reads V[1]+Pt) -- disjoint, no extra barrier needed.
  float* const OTm = (float*)SM;               // 16 x [32q][32h] f32 = 64KB
  float* const Lm  = (float*)(SM + 65536);     // [16 qk-waves][32 q]
#pragma unroll
  for (int ht2 = 0; ht2 < 2; ++ht2)
#pragma unroll
    for (int qs = 0; qs < 2; ++qs) {
      float4 o4;
      o4.x = O[ht2][qs][0]; o4.y = O[ht2][qs][1];
      o4.z = O[ht2][qs][2]; o4.w = O[ht2][qs][3];
      // sub-array id: (pg*2 + hh)*4 + ks2 ; within: [16qs+li][32h]
      *(float4*)&OTm[(((qg * 2 + hh) * 4 + ks2) << 10)
                     + (16 * qs + li) * 32 + 16 * ht2 + 4 * g] = o4;
    }
  if (g == 0) { Lm[w * 32 + li] = lp0; Lm[w * 32 + 16 + li] = lp1; }
  __syncthreads();

  // final: thread t -> q = t>>4 (64), hseg = (t&15)*4; sum 4 key-slices.
  {
    const int q = t >> 4, hseg = (t & 15) << 2;
    const int qq = q & 31, qgf = q >> 5;
    const int hhf = hseg >> 5, hsub = hseg & 31;
    float lF = 0.f;
#pragma unroll
    for (int kff = 0; kff < 8; ++kff) lF += Lm[(qgf + 2 * kff) * 32 + qq];
    float4 a = {0.f, 0.f, 0.f, 0.f};
#pragma unroll
    for (int k2 = 0; k2 < 4; ++k2) {
      const float* Ob = OTm + (((qgf * 2 + hhf) * 4 + k2) << 10) + qq * 32 + hsub;
      float4 u = *(const float4*)Ob;
      a.x += u.x; a.y += u.y; a.z += u.z; a.w += u.w;
    }
    const float inv = 1.f / lF;
    a.x *= inv; a.y *= inv; a.z *= inv; a.w *= inv;
    *(float4*)(out + (b * SEQ + q0 + q) * HS + hseg) = a;
  }
}

// ---------------------------------------------------------------------------
extern "C" void kernel_launch(void* const* d_in, const int* in_sizes, int n_in,
                              void* d_out, int out_size, void* d_ws,
                              size_t ws_size, hipStream_t stream) {
  const float* x  = (const float*)d_in[0];
  const float* Wk = (const float*)d_in[1];
  const float* Wq = (const float*)d_in[2];
  const float* Wv = (const float*)d_in[3];
  float* out = (float*)d_out;

  unsigned short* us = (unsigned short*)d_ws;
  unsigned short* qh = us + 0 * (1 << 20);   // [B][N][H] bf16 hi
  unsigned short* ql = us + 1 * (1 << 20);   // [B][N][H] bf16 lo
  unsigned short* kh = us + 2 * (1 << 20);
  unsigned short* kl = us + 3 * (1 << 20);
  unsigned short* vt = us + 4 * (1 << 20);   // [B][H][N] bf16
  unsigned short* Wh = us + 5 * (1 << 20);   // [192][1024] bf16 hi
  unsigned short* Wl = Wh + 192 * 1024;      // [192][1024] bf16 lo

  wprep<<<192, 256, 0, stream>>>(Wk, Wq, Wv, Wh, Wl);
  qkv_x1<<<512, 512, 0, stream>>>(x, Wh, Wl, qh, ql, kh, kl, vt);
  attn_mfma<<<dim3(64, NB), 1024, 0, stream>>>(qh, ql, kh, kl, vt, out);
}